// Round 4
// baseline (227.073 us; speedup 1.0000x reference)
//
#include <hip/hip_runtime.h>
#include <stdint.h>

typedef unsigned int uint32;
typedef unsigned char u8;
typedef int v4i __attribute__((ext_vector_type(4)));

#define BB 64
#define CC 256
#define OO 256
#define HH 28
#define WW 28
#define HWP 784           // 28*28
#define NWT 589824        // 256*256*9
#define HP 30             // padded spatial (1-px halo each side)
#define XBSTR (HP * HP * 256)   // 230,400 B per padded batch image
#define WTAP (256 * 256)        // 65,536 B per weight tap panel

// ---------------------------------------------------------------------------
// Kernel 1: cast + transpose + pad activations.
// xi8[b][hp][wp][c] = sign(x[b][c][hp-1][wp-1]) as i8 (+1 / 0xFF), with the
// 1-pixel border (hp,wp in {0,29}) written as literal 0 = the conv zero-pad.
// ---------------------------------------------------------------------------
__global__ __launch_bounds__(256) void cast_x_kernel(
    const float* __restrict__ x, u8* __restrict__ xi8) {
  const int hp = blockIdx.x;       // 0..29 padded row
  const int b  = blockIdx.y;       // 0..63
  const int tid = threadIdx.x;
  const int wp = tid & 31;         // 0..31 (30,31 idle)
  const int cq0 = tid >> 5;        // 0..7
  if (wp >= HP) return;
  u8* row = xi8 + (size_t)b * XBSTR + (size_t)(hp * HP + wp) * 256;
  const bool interior = (hp >= 1) && (hp <= 28) && (wp >= 1) && (wp <= 28);
  const float* xp =
      x + (((size_t)b * 256) * 28 + (hp - 1)) * 28 + (wp - 1);  // + c*784
#pragma unroll
  for (int it = 0; it < 8; ++it) {
    const int cq = it * 8 + cq0;   // c-quad 0..63
    uint32 v = 0;
    if (interior) {
      const float* p = xp + (size_t)(cq * 4) * HWP;
      uint32 b0 = (p[0] > 0.f) ? 0x01u : 0xFFu;
      uint32 b1 = (p[HWP] > 0.f) ? 0x01u : 0xFFu;
      uint32 b2 = (p[2 * HWP] > 0.f) ? 0x01u : 0xFFu;
      uint32 b3 = (p[3 * HWP] > 0.f) ? 0x01u : 0xFFu;
      v = b0 | (b1 << 8) | (b2 << 16) | (b3 << 24);
    }
    *(uint32*)(row + cq * 4) = v;
  }
}

// ---------------------------------------------------------------------------
// Kernel 2: weight sign -> i8 tap panels.  wi8[t][o][c] = sign(M + rv.Z)
// (rsqrt normalizer is positive, so sign(w) = sign(m + rv.z) — proven R4-R6).
// ---------------------------------------------------------------------------
__global__ __launch_bounds__(256) void cast_w_kernel(
    const float* __restrict__ M, const float* __restrict__ Z,
    const float* __restrict__ rv, u8* __restrict__ wi8) {
  __shared__ float sacc[2304];
  const int o = blockIdx.x;
  const int tid = threadIdx.x;
  const size_t base = (size_t)o * 2304;
  float r[8];
#pragma unroll
  for (int k = 0; k < 8; ++k) r[k] = rv[k];
#pragma unroll
  for (int ii = 0; ii < 9; ++ii) {
    int i = tid + ii * 256;  // 2304 = 9*256 exactly
    float s = M[base + i];
#pragma unroll
    for (int k = 0; k < 8; ++k) s += r[k] * Z[(size_t)k * NWT + base + i];
    sacc[i] = s;
  }
  __syncthreads();
  const int c = tid;  // M index i = o*2304 + c*9 + t  (t = kh*3+kw = tap)
#pragma unroll
  for (int t = 0; t < 9; ++t) {
    float s = sacc[c * 9 + t];
    wi8[((size_t)t * 256 + o) * 256 + c] = (s > 0.f) ? (u8)1 : (u8)0xFF;
  }
}

// ---------------------------------------------------------------------------
// Kernel 3 (R4): i8 MFMA implicit-GEMM conv — builtin MFMA.
//
// R3 post-mortem: raw `asm("v_mfma_i32_16x16x64_i8 ...")` failed correctness
// (absmax 70.9/468). Full offline re-audit of every index map (A tap deltas,
// B panel layout, k-map symmetry, C/D map) found no software bug; the
// remaining suspects are hazards the compiler cannot see through opaque asm:
//   (1) v_mov acc-init (VALU) -> first MFMA SrcC read: requires wait states,
//       inserted only for intrinsic MFMAs. Stale SrcC = garbage baked in.
//   (2) final MFMA write -> epilogue VALU read: 16 cy of s_nop was a guess.
// Fix: __builtin_amdgcn_mfma_i32_16x16x64_i8 — compiler owns hazard NOPs,
// aligned register classes, scheduling. Data layout byte-identical to R3,
// so pass/fail cleanly discriminates hazard-theory vs layout-theory.
//
// Math: out[b,o,h,w] = alpha[o] * sum_{t,c} sign(x)*sign(w), exact in i8
// (+1/-1, pad=0) -> i32. Per wave: 112 pixels x 64 o = 7x4 tiles. K-loop:
// 9 taps x 4 k-steps(64c). A lane map: row m=l&15 (pixel), k-bytes
// (l>>4)*16+[0..16) in c; B mirror (col n=l&15 = o) — identical k map on
// both sides, so any per-instruction k permutation cancels in the dot
// product. C/D (HW-verified, dtype-independent): col=lane&15 (o),
// row=(lane>>4)*4+reg (pixel). Epilogue: float4 stores.
//
// Grid: 7 pix-blocks x 4 o-quarters x 64 b = 1792 single-wave blocks.
// No LDS, no barriers. Per k-step: 11 x 16B loads (L2-resident wi8 590KB)
// vs 28 MFMAs (~573 cy/SIMD) -> MFMA-bound. i8 ceiling floor = 15.0 µs.
// ---------------------------------------------------------------------------
__global__ __launch_bounds__(64, 2) void conv_mfma_kernel(
    const u8* __restrict__ xi8, const u8* __restrict__ wi8,
    const float* __restrict__ alpha, float* __restrict__ out) {
  const int lane = threadIdx.x;
  const int l15 = lane & 15;
  const int lk  = lane >> 4;       // 0..3
  const int pixb = blockIdx.x * 112;
  const int wv   = blockIdx.y;     // o-quarter 0..3
  const int b    = blockIdx.z;

  // Per-lane A voffsets for the 7 m-tiles at tap (0,0); advanced per tap.
  int aoff[7];
#pragma unroll
  for (int mt = 0; mt < 7; ++mt) {
    int p = pixb + mt * 16 + l15;        // pixel this lane's A-row covers
    int h = p / 28, w = p - h * 28;
    aoff[mt] = (h * HP + w) * 256 + lk * 16;
  }
  const u8* Ab = xi8 + (size_t)b * XBSTR;        // uniform SGPR base
  const u8* Bt = wi8 + wv * (64 * 256);          // + tap*WTAP per tap
  const int bvoff = l15 * 256 + lk * 16;

  float aval[4];
#pragma unroll
  for (int ot = 0; ot < 4; ++ot) aval[ot] = alpha[wv * 64 + ot * 16 + l15];

  v4i acc[7][4];
#pragma unroll
  for (int mt = 0; mt < 7; ++mt)
#pragma unroll
    for (int ot = 0; ot < 4; ++ot) acc[mt][ot] = v4i{0, 0, 0, 0};

  for (int tap = 0; tap < 9; ++tap) {
#pragma unroll
    for (int ks = 0; ks < 4; ++ks) {
      v4i Bf[4];
#pragma unroll
      for (int ot = 0; ot < 4; ++ot)
        Bf[ot] = *(const v4i*)(Bt + (bvoff + ot * 4096 + ks * 64));
      v4i Af[7];
#pragma unroll
      for (int mt = 0; mt < 7; ++mt)
        Af[mt] = *(const v4i*)(Ab + (aoff[mt] + ks * 64));
#pragma unroll
      for (int mt = 0; mt < 7; ++mt)
#pragma unroll
        for (int ot = 0; ot < 4; ++ot)
          acc[mt][ot] = __builtin_amdgcn_mfma_i32_16x16x64_i8(
              Af[mt], Bf[ot], acc[mt][ot], 0, 0, 0);
    }
    // tap spatial deltas: +256 within a kernel row, +7168 at row wrap
    const int del = (tap == 2 || tap == 5) ? 7168 : 256;
#pragma unroll
    for (int mt = 0; mt < 7; ++mt) aoff[mt] += del;
    Bt += WTAP;
  }

#pragma unroll
  for (int mt = 0; mt < 7; ++mt) {
    const int prow = pixb + mt * 16 + lk * 4;   // + reg q = 4 consecutive pix
#pragma unroll
    for (int ot = 0; ot < 4; ++ot) {
      float* op = out +
          ((size_t)b * 256 + (wv * 64 + ot * 16 + l15)) * HWP + prow;
      float4 vst;
      vst.x = aval[ot] * (float)acc[mt][ot][0];
      vst.y = aval[ot] * (float)acc[mt][ot][1];
      vst.z = aval[ot] * (float)acc[mt][ot][2];
      vst.w = aval[ot] * (float)acc[mt][ot][3];
      *(float4*)op = vst;   // 16B aligned: prow % 4 == 0, row stride 3136B
    }
  }
}

// ---------------------------------------------------------------------------
extern "C" void kernel_launch(void* const* d_in, const int* in_sizes, int n_in,
                              void* d_out, int out_size, void* d_ws,
                              size_t ws_size, hipStream_t stream) {
  const float* x     = (const float*)d_in[0];  // (64,256,28,28)
  const float* M     = (const float*)d_in[1];  // (256,256,3,3)
  const float* Z     = (const float*)d_in[2];  // (8,256,256,3,3)
  const float* alpha = (const float*)d_in[3];  // (256,1,1)
  const float* rv    = (const float*)d_in[4];  // (1,8)
  float* out = (float*)d_out;                  // (64,256,28,28)

  u8* xi8 = (u8*)d_ws;                          // 14,745,600 B padded NHWC
  u8* wi8 = (u8*)d_ws + 14745600;               // 589,824 B tap panels

  cast_x_kernel<<<dim3(HP, BB), 256, 0, stream>>>(x, xi8);
  cast_w_kernel<<<dim3(256), 256, 0, stream>>>(M, Z, rv, wi8);
  conv_mfma_kernel<<<dim3(7, 4, BB), 64, 0, stream>>>(xi8, wi8, alpha, out);
}

// Round 5
// 165.368 us; speedup vs baseline: 1.3731x; 1.3731x over previous
//
#include <hip/hip_runtime.h>
#include <stdint.h>

typedef unsigned int uint32;
typedef unsigned char u8;
typedef int v4i __attribute__((ext_vector_type(4)));

#define BB 64
#define CC 256
#define OO 256
#define HH 28
#define WW 28
#define HWP 784           // 28*28
#define NWT 589824        // 256*256*9
#define HP 30             // padded spatial (1-px halo each side)
#define XBSTR (HP * HP * 256)   // 230,400 B per padded batch image
#define WTAP (256 * 256)        // 65,536 B per weight tap panel
#define PPIX 272          // LDS bytes per pixel (256 + 16 pad -> 2-way max)

// ---------------------------------------------------------------------------
// Kernel 1 (R5): cast + transpose + pad activations, LDS-coalesced writes.
// Same values as R4 (verified exact); only the store path changed: R4 wrote
// 4B/lane at 256B stride (scatter L2 had to merge). Now each (b,hp) row is
// built in a padded LDS tile (260B/pixel; bank = 65p+cq -> conflict-free)
// and flushed as 480 contiguous 16B chunks (7,680 B fully coalesced).
// ---------------------------------------------------------------------------
__global__ __launch_bounds__(256) void cast_x_kernel(
    const float* __restrict__ x, u8* __restrict__ xi8) {
  __shared__ u8 srow[30 * 260];
  const int hp = blockIdx.x;       // 0..29 padded row
  const int b  = blockIdx.y;       // 0..63
  const int tid = threadIdx.x;
  const int wp = tid & 31;         // 0..31 (30,31 idle on compute)
  const int cq0 = tid >> 5;        // 0..7
  const bool interior = (hp >= 1) && (hp <= 28) && (wp >= 1) && (wp <= 28);
  const float* xp =
      x + (((size_t)b * 256) * 28 + (hp - 1)) * 28 + (wp - 1);  // + c*784
  if (wp < HP) {
#pragma unroll
    for (int it = 0; it < 8; ++it) {
      const int cq = it * 8 + cq0;   // c-quad 0..63
      uint32 v = 0;
      if (interior) {
        const float* p = xp + (size_t)(cq * 4) * HWP;
        uint32 b0 = (p[0] > 0.f) ? 0x01u : 0xFFu;
        uint32 b1 = (p[HWP] > 0.f) ? 0x01u : 0xFFu;
        uint32 b2 = (p[2 * HWP] > 0.f) ? 0x01u : 0xFFu;
        uint32 b3 = (p[3 * HWP] > 0.f) ? 0x01u : 0xFFu;
        v = b0 | (b1 << 8) | (b2 << 16) | (b3 << 24);
      }
      *(uint32*)(&srow[wp * 260 + cq * 4]) = v;
    }
  }
  __syncthreads();
  u8* rowbase = xi8 + (size_t)b * XBSTR + (size_t)hp * 7680;
#pragma unroll
  for (int i = 0; i < 2; ++i) {
    int c = tid + i * 256;           // 16B chunk id, 0..479
    if (c < 480) {
      uint4 v = *(const uint4*)(&srow[(c >> 4) * 260 + (c & 15) * 16]);
      *(uint4*)(rowbase + (size_t)c * 16) = v;
    }
  }
}

// ---------------------------------------------------------------------------
// Kernel 2: weight sign -> i8 tap panels.  wi8[t][o][c] = sign(M + rv.Z)
// (rsqrt normalizer is positive — proven). Unchanged from R4 (verified).
// ---------------------------------------------------------------------------
__global__ __launch_bounds__(256) void cast_w_kernel(
    const float* __restrict__ M, const float* __restrict__ Z,
    const float* __restrict__ rv, u8* __restrict__ wi8) {
  __shared__ float sacc[2304];
  const int o = blockIdx.x;
  const int tid = threadIdx.x;
  const size_t base = (size_t)o * 2304;
  float r[8];
#pragma unroll
  for (int k = 0; k < 8; ++k) r[k] = rv[k];
#pragma unroll
  for (int ii = 0; ii < 9; ++ii) {
    int i = tid + ii * 256;  // 2304 = 9*256 exactly
    float s = M[base + i];
#pragma unroll
    for (int k = 0; k < 8; ++k) s += r[k] * Z[(size_t)k * NWT + base + i];
    sacc[i] = s;
  }
  __syncthreads();
  const int c = tid;  // M index i = o*2304 + c*9 + t  (t = kh*3+kw = tap)
#pragma unroll
  for (int t = 0; t < 9; ++t) {
    float s = sacc[c * 9 + t];
    wi8[((size_t)t * 256 + o) * 256 + c] = (s > 0.f) ? (u8)1 : (u8)0xFF;
  }
}

// ---------------------------------------------------------------------------
// Kernel 3 (R5): i8 MFMA implicit-GEMM conv, LDS-staged activations.
//
// R4 post-mortem: math exact (absmax 0.0, hazard theory confirmed) but
// FETCH_SIZE = 227 MB (~15x unique bytes): 4 o-quarter blocks x 9 taps
// re-read xi8 through 8 non-coherent XCD L2s -> HBM over-fetch victim at
// MfmaUtil 11.7%. Fix = Guideline 3: one block now covers ALL 256 o
// (4 waves x 64 o) over 112 shared pixels and stages its 6 padded rows
// (180 px x 256B) in LDS ONCE. Activation HBM: 448 x 46 KB = 20.6 MB.
//
// LDS layout: 272 B/pixel (16B pad). A-read: 16 lanes at 272B stride ->
// bank step 68 dwords = 4i mod 32 -> worst 2-way conflict (free, m136).
// Tap walk: +272 per kw step, +7616 on kernel-row wrap (uniform deltas,
// same verified scheme as R4's 256/7168). B: L2-resident (590 KB).
//
// Per k-step/wave: 7 ds_read_b128 + 4 global 16B + 28 MFMAs; 2 blocks/CU
// (launch_bounds(256,2)) -> 2 waves/SIMD co-schedule. MFMA floor 15.0 µs;
// grid 448 = 1.75 blocks/CU -> ~17 µs balanced target.
// ---------------------------------------------------------------------------
__global__ __launch_bounds__(256, 2) void conv_mfma_kernel(
    const u8* __restrict__ xi8, const u8* __restrict__ wi8,
    const float* __restrict__ alpha, float* __restrict__ out) {
  __shared__ u8 albs[6 * 30 * PPIX];  // 48,960 B
  const int tid = threadIdx.x;
  const int lane = tid & 63;
  const int wv = tid >> 6;         // wave 0..3 -> o-quarter
  const int l15 = lane & 15;
  const int lk  = lane >> 4;       // 0..3
  const int pixb = blockIdx.x * 112;
  const int h0   = blockIdx.x * 4;  // first output image row of this block
  const int b    = blockIdx.y;

  // Stage 6 padded rows (2880 x 16B chunks) global->LDS, 272B pixel stride.
  // Global side contiguous/coalesced; LDS write 16 chunks/pixel contiguous.
  {
    const u8* gsrc = xi8 + (size_t)b * XBSTR + (size_t)h0 * 7680;
#pragma unroll
    for (int i = 0; i < 12; ++i) {
      int c = tid + i * 256;
      if (c < 2880) {
        uint4 v = *(const uint4*)(gsrc + (size_t)c * 16);
        *(uint4*)(&albs[(c >> 4) * PPIX + (c & 15) * 16]) = v;
      }
    }
  }
  __syncthreads();

  // Per-lane LDS offsets for the 7 m-tiles at tap (0,0); advanced per tap.
  int lbase[7];
#pragma unroll
  for (int mt = 0; mt < 7; ++mt) {
    int p = pixb + mt * 16 + l15;        // output pixel of this A-row
    int h = p / 28, w = p - h * 28;
    lbase[mt] = ((h - h0) * 30 + w) * PPIX + lk * 16;  // tap(0,0) input px
  }
  const u8* Bt = wi8 + wv * (64 * 256);  // + tap*WTAP per tap
  const int bvoff = l15 * 256 + lk * 16;

  float aval[4];
#pragma unroll
  for (int ot = 0; ot < 4; ++ot) aval[ot] = alpha[wv * 64 + ot * 16 + l15];

  v4i acc[7][4];
#pragma unroll
  for (int mt = 0; mt < 7; ++mt)
#pragma unroll
    for (int ot = 0; ot < 4; ++ot) acc[mt][ot] = v4i{0, 0, 0, 0};

  for (int tap = 0; tap < 9; ++tap) {
#pragma unroll
    for (int ks = 0; ks < 4; ++ks) {
      v4i Bf[4];
#pragma unroll
      for (int ot = 0; ot < 4; ++ot)
        Bf[ot] = *(const v4i*)(Bt + (bvoff + ot * 4096 + ks * 64));
      v4i Af[7];
#pragma unroll
      for (int mt = 0; mt < 7; ++mt)
        Af[mt] = *(const v4i*)(&albs[lbase[mt] + ks * 64]);
#pragma unroll
      for (int mt = 0; mt < 7; ++mt)
#pragma unroll
        for (int ot = 0; ot < 4; ++ot)
          acc[mt][ot] = __builtin_amdgcn_mfma_i32_16x16x64_i8(
              Af[mt], Bf[ot], acc[mt][ot], 0, 0, 0);
    }
    // tap deltas in LDS coords: +272 within kernel row, +7616 at row wrap
    const int del = (tap == 2 || tap == 5) ? 7616 : PPIX;
#pragma unroll
    for (int mt = 0; mt < 7; ++mt) lbase[mt] += del;
    Bt += WTAP;
  }

  // Epilogue: C/D map col=lane&15 (o), row=(lane>>4)*4+reg (pixel). float4
  // stores, 16B aligned (prow % 4 == 0). Verified exact in R4.
#pragma unroll
  for (int mt = 0; mt < 7; ++mt) {
    const int prow = pixb + mt * 16 + lk * 4;
#pragma unroll
    for (int ot = 0; ot < 4; ++ot) {
      float* op = out +
          ((size_t)b * 256 + (wv * 64 + ot * 16 + l15)) * HWP + prow;
      float4 vst;
      vst.x = aval[ot] * (float)acc[mt][ot][0];
      vst.y = aval[ot] * (float)acc[mt][ot][1];
      vst.z = aval[ot] * (float)acc[mt][ot][2];
      vst.w = aval[ot] * (float)acc[mt][ot][3];
      *(float4*)op = vst;
    }
  }
}

// ---------------------------------------------------------------------------
extern "C" void kernel_launch(void* const* d_in, const int* in_sizes, int n_in,
                              void* d_out, int out_size, void* d_ws,
                              size_t ws_size, hipStream_t stream) {
  const float* x     = (const float*)d_in[0];  // (64,256,28,28)
  const float* M     = (const float*)d_in[1];  // (256,256,3,3)
  const float* Z     = (const float*)d_in[2];  // (8,256,256,3,3)
  const float* alpha = (const float*)d_in[3];  // (256,1,1)
  const float* rv    = (const float*)d_in[4];  // (1,8)
  float* out = (float*)d_out;                  // (64,256,28,28)

  u8* xi8 = (u8*)d_ws;                          // 14,745,600 B padded NHWC
  u8* wi8 = (u8*)d_ws + 14745600;               // 589,824 B tap panels

  cast_x_kernel<<<dim3(HP, BB), 256, 0, stream>>>(x, xi8);
  cast_w_kernel<<<dim3(256), 256, 0, stream>>>(M, Z, rv, wi8);
  conv_mfma_kernel<<<dim3(7, BB), 256, 0, stream>>>(xi8, wi8, alpha, out);
}

// Round 6
// 164.898 us; speedup vs baseline: 1.3770x; 1.0028x over previous
//
#include <hip/hip_runtime.h>
#include <stdint.h>

typedef unsigned int uint32;
typedef unsigned char u8;
typedef int v4i __attribute__((ext_vector_type(4)));

#define BB 64
#define CC 256
#define OO 256
#define HH 28
#define WW 28
#define HWP 784           // 28*28
#define NWT 589824        // 256*256*9
#define HP 30             // padded spatial (1-px halo each side)
#define XBSTR (HP * HP * 256)   // 230,400 B per padded batch image
#define WTAP (256 * 256)        // 65,536 B per weight tap panel
#define PPIX 272          // LDS bytes per pixel (256 + 16 pad)

// ---------------------------------------------------------------------------
// Kernel 1: cast + transpose + pad activations, LDS-coalesced writes.
// (unchanged from R5 — verified exact; store path fully coalesced)
// ---------------------------------------------------------------------------
__global__ __launch_bounds__(256) void cast_x_kernel(
    const float* __restrict__ x, u8* __restrict__ xi8) {
  __shared__ u8 srow[30 * 260];
  const int hp = blockIdx.x;       // 0..29 padded row
  const int b  = blockIdx.y;       // 0..63
  const int tid = threadIdx.x;
  const int wp = tid & 31;         // 0..31 (30,31 idle on compute)
  const int cq0 = tid >> 5;        // 0..7
  const bool interior = (hp >= 1) && (hp <= 28) && (wp >= 1) && (wp <= 28);
  const float* xp =
      x + (((size_t)b * 256) * 28 + (hp - 1)) * 28 + (wp - 1);  // + c*784
  if (wp < HP) {
#pragma unroll
    for (int it = 0; it < 8; ++it) {
      const int cq = it * 8 + cq0;   // c-quad 0..63
      uint32 v = 0;
      if (interior) {
        const float* p = xp + (size_t)(cq * 4) * HWP;
        uint32 b0 = (p[0] > 0.f) ? 0x01u : 0xFFu;
        uint32 b1 = (p[HWP] > 0.f) ? 0x01u : 0xFFu;
        uint32 b2 = (p[2 * HWP] > 0.f) ? 0x01u : 0xFFu;
        uint32 b3 = (p[3 * HWP] > 0.f) ? 0x01u : 0xFFu;
        v = b0 | (b1 << 8) | (b2 << 16) | (b3 << 24);
      }
      *(uint32*)(&srow[wp * 260 + cq * 4]) = v;
    }
  }
  __syncthreads();
  u8* rowbase = xi8 + (size_t)b * XBSTR + (size_t)hp * 7680;
#pragma unroll
  for (int i = 0; i < 2; ++i) {
    int c = tid + i * 256;           // 16B chunk id, 0..479
    if (c < 480) {
      uint4 v = *(const uint4*)(&srow[(c >> 4) * 260 + (c & 15) * 16]);
      *(uint4*)(rowbase + (size_t)c * 16) = v;
    }
  }
}

// ---------------------------------------------------------------------------
// Kernel 2: weight sign -> i8 tap panels.  wi8[t][o][c] = sign(M + rv.Z).
// (unchanged — verified exact)
// ---------------------------------------------------------------------------
__global__ __launch_bounds__(256) void cast_w_kernel(
    const float* __restrict__ M, const float* __restrict__ Z,
    const float* __restrict__ rv, u8* __restrict__ wi8) {
  __shared__ float sacc[2304];
  const int o = blockIdx.x;
  const int tid = threadIdx.x;
  const size_t base = (size_t)o * 2304;
  float r[8];
#pragma unroll
  for (int k = 0; k < 8; ++k) r[k] = rv[k];
#pragma unroll
  for (int ii = 0; ii < 9; ++ii) {
    int i = tid + ii * 256;  // 2304 = 9*256 exactly
    float s = M[base + i];
#pragma unroll
    for (int k = 0; k < 8; ++k) s += r[k] * Z[(size_t)k * NWT + base + i];
    sacc[i] = s;
  }
  __syncthreads();
  const int c = tid;  // M index i = o*2304 + c*9 + t  (t = kh*3+kw = tap)
#pragma unroll
  for (int t = 0; t < 9; ++t) {
    float s = sacc[c * 9 + t];
    wi8[((size_t)t * 256 + o) * 256 + c] = (s > 0.f) ? (u8)1 : (u8)0xFF;
  }
}

// ---------------------------------------------------------------------------
// Kernel 3 (R6): i8 MFMA implicit-GEMM conv, LDS-staged A, FULL K-UNROLL.
//
// R5 post-mortem: FETCH fixed (227->12.4 MB) but conv stuck at 53 µs with
// MfmaUtil 21 / VALUBusy 8 / HBM 15 / Occupancy 16 -> latency-bound. The
// rolled tap loop (VGPR_Count=104: no pipeline registers) serialized each
// tap: issue 16 L2 B-loads + 28 ds_reads, drain (~300 cy), then MFMA.
// At ~1.75 waves/SIMD nothing covers the drain -> 3.5x over MFMA makespan.
//
// Fix: #pragma unroll on taps (trip 9, all offsets compile-time; the tap
// walk (kh*30+kw)*PPIX folds into the verified 272/7616 deltas). The k-loop
// has NO barriers (LDS read-only after the one staging __syncthreads), so
// the unrolled body is one straight-line 144-MFMA block and the scheduler
// can hoist tap t+1's loads under tap t's MFMAs, bounded by the 256-VGPR
// budget of __launch_bounds__(256,2). acc 112 + ks-group 44 + lookahead
// fits. 2 blocks/CU residency is makespan-optimal (ceil(448/256)=2 rounds).
//
// Everything else (layouts, epilogue C/D map, staging) byte-identical to
// R5 (absmax 0.0 verified).
// ---------------------------------------------------------------------------
__global__ __launch_bounds__(256, 2) void conv_mfma_kernel(
    const u8* __restrict__ xi8, const u8* __restrict__ wi8,
    const float* __restrict__ alpha, float* __restrict__ out) {
  __shared__ u8 albs[6 * 30 * PPIX];  // 48,960 B
  const int tid = threadIdx.x;
  const int lane = tid & 63;
  const int wv = tid >> 6;         // wave 0..3 -> o-quarter
  const int l15 = lane & 15;
  const int lk  = lane >> 4;       // 0..3
  const int pixb = blockIdx.x * 112;
  const int h0   = blockIdx.x * 4;  // first output image row of this block
  const int b    = blockIdx.y;

  // Stage 6 padded rows (2880 x 16B chunks) global->LDS, 272B pixel stride.
  {
    const u8* gsrc = xi8 + (size_t)b * XBSTR + (size_t)h0 * 7680;
#pragma unroll
    for (int i = 0; i < 12; ++i) {
      int c = tid + i * 256;
      if (c < 2880) {
        uint4 v = *(const uint4*)(gsrc + (size_t)c * 16);
        *(uint4*)(&albs[(c >> 4) * PPIX + (c & 15) * 16]) = v;
      }
    }
  }
  __syncthreads();

  // Per-lane LDS base for the 7 m-tiles at tap (0,0); taps add constants.
  int lb[7];
#pragma unroll
  for (int mt = 0; mt < 7; ++mt) {
    int p = pixb + mt * 16 + l15;        // output pixel of this A-row
    int h = p / 28, w = p - h * 28;
    lb[mt] = ((h - h0) * 30 + w) * PPIX + lk * 16;  // tap(0,0) input px
  }
  const u8* Bb = wi8 + wv * (64 * 256);
  const int bvoff = l15 * 256 + lk * 16;

  float aval[4];
#pragma unroll
  for (int ot = 0; ot < 4; ++ot) aval[ot] = alpha[wv * 64 + ot * 16 + l15];

  v4i acc[7][4];
#pragma unroll
  for (int mt = 0; mt < 7; ++mt)
#pragma unroll
    for (int ot = 0; ot < 4; ++ot) acc[mt][ot] = v4i{0, 0, 0, 0};

#pragma unroll
  for (int tap = 0; tap < 9; ++tap) {
    const int kh = tap / 3, kw = tap - kh * 3;
    const int toff = (kh * 30 + kw) * PPIX;       // compile-time per tap
    const u8* Bt = Bb + (size_t)tap * WTAP;       // compile-time per tap
#pragma unroll
    for (int ks = 0; ks < 4; ++ks) {
      v4i Bf[4];
#pragma unroll
      for (int ot = 0; ot < 4; ++ot)
        Bf[ot] = *(const v4i*)(Bt + (bvoff + ot * 4096 + ks * 64));
      v4i Af[7];
#pragma unroll
      for (int mt = 0; mt < 7; ++mt)
        Af[mt] = *(const v4i*)(&albs[lb[mt] + toff + ks * 64]);
#pragma unroll
      for (int mt = 0; mt < 7; ++mt)
#pragma unroll
        for (int ot = 0; ot < 4; ++ot)
          acc[mt][ot] = __builtin_amdgcn_mfma_i32_16x16x64_i8(
              Af[mt], Bf[ot], acc[mt][ot], 0, 0, 0);
    }
  }

  // Epilogue: C/D map col=lane&15 (o), row=(lane>>4)*4+reg (pixel). float4
  // stores, 16B aligned (prow % 4 == 0). Verified exact in R4/R5.
#pragma unroll
  for (int mt = 0; mt < 7; ++mt) {
    const int prow = pixb + mt * 16 + lk * 4;
#pragma unroll
    for (int ot = 0; ot < 4; ++ot) {
      float* op = out +
          ((size_t)b * 256 + (wv * 64 + ot * 16 + l15)) * HWP + prow;
      float4 vst;
      vst.x = aval[ot] * (float)acc[mt][ot][0];
      vst.y = aval[ot] * (float)acc[mt][ot][1];
      vst.z = aval[ot] * (float)acc[mt][ot][2];
      vst.w = aval[ot] * (float)acc[mt][ot][3];
      *(float4*)op = vst;
    }
  }
}

// ---------------------------------------------------------------------------
extern "C" void kernel_launch(void* const* d_in, const int* in_sizes, int n_in,
                              void* d_out, int out_size, void* d_ws,
                              size_t ws_size, hipStream_t stream) {
  const float* x     = (const float*)d_in[0];  // (64,256,28,28)
  const float* M     = (const float*)d_in[1];  // (256,256,3,3)
  const float* Z     = (const float*)d_in[2];  // (8,256,256,3,3)
  const float* alpha = (const float*)d_in[3];  // (256,1,1)
  const float* rv    = (const float*)d_in[4];  // (1,8)
  float* out = (float*)d_out;                  // (64,256,28,28)

  u8* xi8 = (u8*)d_ws;                          // 14,745,600 B padded NHWC
  u8* wi8 = (u8*)d_ws + 14745600;               // 589,824 B tap panels

  cast_x_kernel<<<dim3(HP, BB), 256, 0, stream>>>(x, xi8);
  cast_w_kernel<<<dim3(256), 256, 0, stream>>>(M, Z, rv, wi8);
  conv_mfma_kernel<<<dim3(7, BB), 256, 0, stream>>>(xi8, wi8, alpha, out);
}

// Round 7
// 164.778 us; speedup vs baseline: 1.3781x; 1.0007x over previous
//
#include <hip/hip_runtime.h>
#include <stdint.h>

typedef unsigned int uint32;
typedef unsigned char u8;
typedef int v4i __attribute__((ext_vector_type(4)));

#define BB 64
#define CC 256
#define OO 256
#define HH 28
#define WW 28
#define HWP 784           // 28*28
#define NWT 589824        // 256*256*9
#define HP 30             // padded spatial (1-px halo each side)
#define XBSTR (HP * HP * 256)   // 230,400 B per padded batch image
#define WTAP (256 * 256)        // 65,536 B per weight tap panel
#define PPIX 272          // LDS bytes per pixel (256 + 16 pad)

// ---------------------------------------------------------------------------
// Kernel 1: cast + transpose + pad activations, LDS-coalesced writes.
// (unchanged from R5 — verified exact; ~15 µs ≈ its 97 MB BW floor)
// ---------------------------------------------------------------------------
__global__ __launch_bounds__(256) void cast_x_kernel(
    const float* __restrict__ x, u8* __restrict__ xi8) {
  __shared__ u8 srow[30 * 260];
  const int hp = blockIdx.x;       // 0..29 padded row
  const int b  = blockIdx.y;       // 0..63
  const int tid = threadIdx.x;
  const int wp = tid & 31;         // 0..31 (30,31 idle on compute)
  const int cq0 = tid >> 5;        // 0..7
  const bool interior = (hp >= 1) && (hp <= 28) && (wp >= 1) && (wp <= 28);
  const float* xp =
      x + (((size_t)b * 256) * 28 + (hp - 1)) * 28 + (wp - 1);  // + c*784
  if (wp < HP) {
#pragma unroll
    for (int it = 0; it < 8; ++it) {
      const int cq = it * 8 + cq0;   // c-quad 0..63
      uint32 v = 0;
      if (interior) {
        const float* p = xp + (size_t)(cq * 4) * HWP;
        uint32 b0 = (p[0] > 0.f) ? 0x01u : 0xFFu;
        uint32 b1 = (p[HWP] > 0.f) ? 0x01u : 0xFFu;
        uint32 b2 = (p[2 * HWP] > 0.f) ? 0x01u : 0xFFu;
        uint32 b3 = (p[3 * HWP] > 0.f) ? 0x01u : 0xFFu;
        v = b0 | (b1 << 8) | (b2 << 16) | (b3 << 24);
      }
      *(uint32*)(&srow[wp * 260 + cq * 4]) = v;
    }
  }
  __syncthreads();
  u8* rowbase = xi8 + (size_t)b * XBSTR + (size_t)hp * 7680;
#pragma unroll
  for (int i = 0; i < 2; ++i) {
    int c = tid + i * 256;           // 16B chunk id, 0..479
    if (c < 480) {
      uint4 v = *(const uint4*)(&srow[(c >> 4) * 260 + (c & 15) * 16]);
      *(uint4*)(rowbase + (size_t)c * 16) = v;
    }
  }
}

// ---------------------------------------------------------------------------
// Kernel 2: weight sign -> i8 tap panels.  wi8[t][o][c] = sign(M + rv.Z).
// (unchanged — verified exact)
// ---------------------------------------------------------------------------
__global__ __launch_bounds__(256) void cast_w_kernel(
    const float* __restrict__ M, const float* __restrict__ Z,
    const float* __restrict__ rv, u8* __restrict__ wi8) {
  __shared__ float sacc[2304];
  const int o = blockIdx.x;
  const int tid = threadIdx.x;
  const size_t base = (size_t)o * 2304;
  float r[8];
#pragma unroll
  for (int k = 0; k < 8; ++k) r[k] = rv[k];
#pragma unroll
  for (int ii = 0; ii < 9; ++ii) {
    int i = tid + ii * 256;  // 2304 = 9*256 exactly
    float s = M[base + i];
#pragma unroll
    for (int k = 0; k < 8; ++k) s += r[k] * Z[(size_t)k * NWT + base + i];
    sacc[i] = s;
  }
  __syncthreads();
  const int c = tid;  // M index i = o*2304 + c*9 + t  (t = kh*3+kw = tap)
#pragma unroll
  for (int t = 0; t < 9; ++t) {
    float s = sacc[c * 9 + t];
    wi8[((size_t)t * 256 + o) * 256 + c] = (s > 0.f) ? (u8)1 : (u8)0xFF;
  }
}

// Load k-group g (tap = g/4, ks = g%4): 7 A-fragments from LDS + 4 B-frags
// from L2. Invoked only from a FULLY-UNROLLED loop, so tap/ks/toff are
// compile-time constants in every clone (rule #20: all static indexing).
#define LOADG(g_, AF, BF)                                                      \
  {                                                                            \
    const int tap_ = (g_) >> 2, ks_ = (g_) & 3;                                \
    const int toff_ =                                                          \
        ((tap_ / 3) * 30 + (tap_ % 3)) * PPIX + ks_ * 64;                      \
    _Pragma("unroll") for (int ot = 0; ot < 4; ++ot)                           \
        (BF)[ot] = *(const v4i*)(Bb + ((size_t)tap_ * WTAP) +                  \
                                 (bvoff + ot * 4096 + ks_ * 64));              \
    _Pragma("unroll") for (int mt = 0; mt < 7; ++mt)                           \
        (AF)[mt] = *(const v4i*)(&albs[lb[mt] + toff_]);                       \
  }

#define MFMAG(AF, BF)                                                          \
  {                                                                            \
    _Pragma("unroll") for (int mt = 0; mt < 7; ++mt)                           \
        _Pragma("unroll") for (int ot = 0; ot < 4; ++ot)                       \
            acc[mt][ot] = __builtin_amdgcn_mfma_i32_16x16x64_i8(               \
                (AF)[mt], (BF)[ot], acc[mt][ot], 0, 0, 0);                     \
  }

// ---------------------------------------------------------------------------
// Kernel 3 (R7): i8 MFMA implicit-GEMM conv — ILP-forced schedule.
//
// R6 post-mortem: full unroll alone was null (56 µs, VGPR_Count=128 — the
// exact 4-waves/EU pressure boundary). The scheduler targeted 4 waves/EU
// occupancy that this grid can never provide (448 blocks x 4 waves = 1.75
// waves/SIMD, GRID-limited) and in exchange issued loads just-in-time ->
// exposed L2/LDS latency at MfmaUtil 19%.
//
// Two forcing functions, same verified data layout (absmax 0.0 in R4-R6):
// 1. amdgpu_waves_per_eu(2,2): tells the truth — max 2 waves/EU — which
//    unlocks the 256-VGPR budget and flips the scheduler from
//    "protect occupancy" to "maximize ILP".
// 2. Explicit depth-1 ping-pong prefetch (A0/B0 vs A1/B1, all static):
//    group g+1's 11 loads issue before group g's 28-MFMA block (~224 cy of
//    issue) — covers LDS ~120 cy and L2 ~200-300 cy by construction.
// Registers: acc 112 + A 2x28 + B 2x16 + addr ~ 230 < 256. One wave
// issuing MFMAs back-to-back saturates its SIMD matrix pipe (needs only
// 1 issue/~20 cy), so 1.75 waves/SIMD suffices once loads are hoisted.
// Target: ~17 µs two-block-CU MFMA makespan.
// ---------------------------------------------------------------------------
__global__ __launch_bounds__(256)
__attribute__((amdgpu_waves_per_eu(2, 2))) void conv_mfma_kernel(
    const u8* __restrict__ xi8, const u8* __restrict__ wi8,
    const float* __restrict__ alpha, float* __restrict__ out) {
  __shared__ u8 albs[6 * 30 * PPIX];  // 48,960 B
  const int tid = threadIdx.x;
  const int lane = tid & 63;
  const int wv = tid >> 6;         // wave 0..3 -> o-quarter
  const int l15 = lane & 15;
  const int lk  = lane >> 4;       // 0..3
  const int pixb = blockIdx.x * 112;
  const int h0   = blockIdx.x * 4;  // first output image row of this block
  const int b    = blockIdx.y;

  // Stage 6 padded rows (2880 x 16B chunks) global->LDS, 272B pixel stride.
  {
    const u8* gsrc = xi8 + (size_t)b * XBSTR + (size_t)h0 * 7680;
#pragma unroll
    for (int i = 0; i < 12; ++i) {
      int c = tid + i * 256;
      if (c < 2880) {
        uint4 v = *(const uint4*)(gsrc + (size_t)c * 16);
        *(uint4*)(&albs[(c >> 4) * PPIX + (c & 15) * 16]) = v;
      }
    }
  }
  __syncthreads();

  // Per-lane LDS base for the 7 m-tiles at tap (0,0); taps add constants.
  int lb[7];
#pragma unroll
  for (int mt = 0; mt < 7; ++mt) {
    int p = pixb + mt * 16 + l15;        // output pixel of this A-row
    int h = p / 28, w = p - h * 28;
    lb[mt] = ((h - h0) * 30 + w) * PPIX + lk * 16;  // tap(0,0) input px
  }
  const u8* Bb = wi8 + wv * (64 * 256);
  const int bvoff = l15 * 256 + lk * 16;

  float aval[4];
#pragma unroll
  for (int ot = 0; ot < 4; ++ot) aval[ot] = alpha[wv * 64 + ot * 16 + l15];

  v4i acc[7][4];
#pragma unroll
  for (int mt = 0; mt < 7; ++mt)
#pragma unroll
    for (int ot = 0; ot < 4; ++ot) acc[mt][ot] = v4i{0, 0, 0, 0};

  // 36 k-groups (9 taps x 4 ks), depth-1 ping-pong software pipeline.
  v4i A0[7], B0[4], A1[7], B1[4];
  LOADG(0, A0, B0);
#pragma unroll
  for (int g = 0; g < 36; g += 2) {
    LOADG(g + 1, A1, B1);          // prefetch odd group
    MFMAG(A0, B0);                 // compute even group (~224 cy issue)
    if (g + 2 < 36) LOADG(g + 2, A0, B0);  // prefetch next even group
    MFMAG(A1, B1);                 // compute odd group
  }

  // Epilogue: C/D map col=lane&15 (o), row=(lane>>4)*4+reg (pixel). float4
  // stores, 16B aligned (prow % 4 == 0). Verified exact in R4-R6.
#pragma unroll
  for (int mt = 0; mt < 7; ++mt) {
    const int prow = pixb + mt * 16 + lk * 4;
#pragma unroll
    for (int ot = 0; ot < 4; ++ot) {
      float* op = out +
          ((size_t)b * 256 + (wv * 64 + ot * 16 + l15)) * HWP + prow;
      float4 vst;
      vst.x = aval[ot] * (float)acc[mt][ot][0];
      vst.y = aval[ot] * (float)acc[mt][ot][1];
      vst.z = aval[ot] * (float)acc[mt][ot][2];
      vst.w = aval[ot] * (float)acc[mt][ot][3];
      *(float4*)op = vst;
    }
  }
}

// ---------------------------------------------------------------------------
extern "C" void kernel_launch(void* const* d_in, const int* in_sizes, int n_in,
                              void* d_out, int out_size, void* d_ws,
                              size_t ws_size, hipStream_t stream) {
  const float* x     = (const float*)d_in[0];  // (64,256,28,28)
  const float* M     = (const float*)d_in[1];  // (256,256,3,3)
  const float* Z     = (const float*)d_in[2];  // (8,256,256,3,3)
  const float* alpha = (const float*)d_in[3];  // (256,1,1)
  const float* rv    = (const float*)d_in[4];  // (1,8)
  float* out = (float*)d_out;                  // (64,256,28,28)

  u8* xi8 = (u8*)d_ws;                          // 14,745,600 B padded NHWC
  u8* wi8 = (u8*)d_ws + 14745600;               // 589,824 B tap panels

  cast_x_kernel<<<dim3(HP, BB), 256, 0, stream>>>(x, xi8);
  cast_w_kernel<<<dim3(256), 256, 0, stream>>>(M, Z, rv, wi8);
  conv_mfma_kernel<<<dim3(7, BB), 256, 0, stream>>>(xi8, wi8, alpha, out);
}